// Round 17
// baseline (112.625 us; speedup 1.0000x reference)
//
#include <hip/hip_runtime.h>
#include <math.h>

#define BB 2
#define LL 4096
#define HH 8
#define DD 64
#define BH (BB*HH)
#define NCHUNK 128
#define CLEN (LL/NCHUNK)     // 32
#define NCB (BH*NCHUNK/4)    // 512 chunk/emit blocks (4 waves each)
#define QP 48          // u=45 padded to 48
#define KP 68          // padded row length (floats) for Q/K tiles
#define MTBLOCKS (BH*LL/4)   // 16384

__device__ __forceinline__ float dot4(float4 a, float4 b) {
    return a.x*b.x + a.y*b.y + a.z*b.z + a.w*b.w;
}

// ---------------------------------------------------------------------------
// D1: blocks 0..NCB-1 = V chunk sums FRONT-placed (hidden in MT ramp;
// r14/15: trailing fused blocks serialize, leading ones hide).
// Blocks NCB.. = MT (one wave per query, XCD-local bh pairing, NIT unroll,
// coalesced fragments; ~53us = random-L2-line-rate floor, r7-12).
// ---------------------------------------------------------------------------
template<int NIT>
__global__ __launch_bounds__(256) void fusedChunkMT(const float* __restrict__ Q,
        const float* __restrict__ K, const int* __restrict__ idx,
        float* __restrict__ M, const float* __restrict__ V,
        float* __restrict__ csum, int u) {
    int t = threadIdx.x;
    if (blockIdx.x < NCB) {
        int id = blockIdx.x * 4 + (t >> 6);               // bh*NCHUNK + c
        int lane = t & 63;
        int c = id & (NCHUNK - 1);
        int bh = id >> 7;
        int h = bh & (HH - 1), b = bh >> 3;
        int l0 = c * CLEN;
        float acc = 0.f;
        for (int i = 0; i < CLEN; ++i)
            acc += V[(((size_t)b * LL + l0 + i) * HH + h) * DD + lane];
        csum[(size_t)id * DD + lane] = acc;
        return;
    }
    int wave = t >> 6;
    int lane = t & 63;
    int w = blockIdx.x - NCB;
    int bh = ((w & 7) << 1) | ((w >> 3) & 1);   // XCD-local bh pair
    int qb = w >> 4;                            // 0..1023
    int g  = (bh << 12) + qb * 4 + wave;        // (b*H+h)*L + l
    int l  = g & (LL - 1);
    int h  = bh & (HH - 1);
    int b  = bh >> 3;
    int grp = lane >> 2, sub = lane & 3;
    const float4* qrow = (const float4*)(Q + (((size_t)b * LL + l) * HH + h) * DD);
    float4 q0 = qrow[0 * 4 + sub];
    float4 q1 = qrow[1 * 4 + sub];
    float4 q2 = qrow[2 * 4 + sub];
    float4 q3 = qrow[3 * 4 + sub];
    const int* ip = idx + (size_t)l * u;

    int  ks[NIT];
    bool act[NIT];
    #pragma unroll
    for (int i = 0; i < NIT; ++i) {
        int s = i * 16 + grp;
        act[i] = (s < u);
        ks[i] = act[i] ? ip[s] : 0;
    }
    const float* kbase = K + ((size_t)b * LL * HH + h) * DD;
    float4 kv[NIT][4];
    #pragma unroll
    for (int i = 0; i < NIT; ++i) {
        const float4* kr = (const float4*)(kbase + (size_t)ks[i] * (HH * DD));
        kv[i][0] = kr[0 * 4 + sub];
        kv[i][1] = kr[1 * 4 + sub];
        kv[i][2] = kr[2 * 4 + sub];
        kv[i][3] = kr[3 * 4 + sub];
    }
    float mx = -INFINITY, sm = 0.f;
    #pragma unroll
    for (int i = 0; i < NIT; ++i) {
        float p = dot4(q0, kv[i][0]) + dot4(q1, kv[i][1])
                + dot4(q2, kv[i][2]) + dot4(q3, kv[i][3]);
        p += __shfl_xor(p, 1, 64);
        p += __shfl_xor(p, 2, 64);
        if (act[i]) { mx = fmaxf(mx, p); sm += p; }
    }
    #pragma unroll
    for (int off = 4; off <= 32; off <<= 1) {
        mx = fmaxf(mx, __shfl_xor(mx, off, 64));
        sm += __shfl_xor(sm, off, 64);
    }
    if (lane == 0) M[g] = mx - sm * (1.0f / LL);
}

// fallbacks for u > 64
__global__ void kernelMGen(const float* __restrict__ Q, const float* __restrict__ K,
                        const int* __restrict__ idx, float* __restrict__ M, int u) {
    int wave = threadIdx.x >> 6;
    int lane = threadIdx.x & 63;
    int g = blockIdx.x * 4 + wave;
    int l  = g & (LL - 1);
    int bh = g >> 12;
    int h  = bh & (HH - 1);
    int b  = bh >> 3;
    int grp = lane >> 2, sub = lane & 3;
    const float4* qrow = (const float4*)(Q + (((size_t)b * LL + l) * HH + h) * DD);
    float4 q0 = qrow[0*4+sub], q1 = qrow[1*4+sub];
    float4 q2 = qrow[2*4+sub], q3 = qrow[3*4+sub];
    const int* ip = idx + (size_t)l * u;
    float mx = -INFINITY, sm = 0.f;
    for (int s0 = 0; s0 < u; s0 += 16) {
        int s = s0 + grp;
        bool act = (s < u);
        int ks = act ? ip[s] : 0;
        const float4* krow = (const float4*)(K + (((size_t)b * LL + ks) * HH + h) * DD);
        float4 k0 = krow[0*4+sub], k1 = krow[1*4+sub];
        float4 k2 = krow[2*4+sub], k3 = krow[3*4+sub];
        float p = dot4(q0, k0) + dot4(q1, k1) + dot4(q2, k2) + dot4(q3, k3);
        p += __shfl_xor(p, 1, 64);
        p += __shfl_xor(p, 2, 64);
        if (act) { mx = fmaxf(mx, p); sm += p; }
    }
    #pragma unroll
    for (int off = 4; off <= 32; off <<= 1) {
        mx = fmaxf(mx, __shfl_xor(mx, off, 64));
        sm += __shfl_xor(sm, off, 64);
    }
    if (lane == 0) M[g] = mx - sm * (1.0f / LL);
}

__global__ void kernelChunkOnly(const float* __restrict__ V, float* __restrict__ csum) {
    int id = blockIdx.x * 4 + (threadIdx.x >> 6);
    int lane = threadIdx.x & 63;
    int c = id & (NCHUNK - 1);
    int bh = id >> 7;
    int h = bh & (HH - 1), b = bh >> 3;
    int l0 = c * CLEN;
    float acc = 0.f;
    for (int i = 0; i < CLEN; ++i)
        acc += V[(((size_t)b * LL + l0 + i) * HH + h) * DD + lane];
    csum[(size_t)id * DD + lane] = acc;
}

// ---------------------------------------------------------------------------
// D2: blocks 0-15 = radix-select top-u per (b,h); blocks 16..16+NCB-1 =
// cumsum emit for ALL rows (self-computed prefix over <=127 chunk sums;
// 512 blocks = 2/CU -> 2x latency hiding vs NCHUNK=64's 1/CU, and half
// the serial 32-row emit chain). Selected rows overwritten by D4.
// ---------------------------------------------------------------------------
__global__ __launch_bounds__(256) void fusedTopKCumsum(const float* __restrict__ M,
        int* __restrict__ Mtop, const float* __restrict__ V,
        const float* __restrict__ csum, float* __restrict__ out, int u) {
    __shared__ unsigned keys[LL];
    __shared__ int hist[4096];
    __shared__ int cidx[LL];
    __shared__ int csum_s[256];
    __shared__ int ctl[4];
    int t = threadIdx.x;

    if (blockIdx.x >= 16) {
        int id = (blockIdx.x - 16) * 4 + (t >> 6);       // bh*NCHUNK + c
        int lane = t & 63;
        int c = id & (NCHUNK - 1);
        int bh = id >> 7;
        int h = bh & (HH - 1), b = bh >> 3;
        float acc = 0.f;
        for (int cc = 0; cc < c; ++cc)
            acc += csum[((size_t)(bh * NCHUNK + cc)) * DD + lane];
        int l0 = c * CLEN;
        for (int i = 0; i < CLEN; ++i) {
            int l = l0 + i;
            acc += V[(((size_t)b * LL + l) * HH + h) * DD + lane];
            out[((size_t)bh * LL + l) * DD + lane] = acc;
        }
        return;
    }

    int bh = blockIdx.x;
    const float* mrow = M + (size_t)bh * LL;
    for (int i = t; i < 4096; i += 256) hist[i] = 0;
    if (t < 4) ctl[t] = 0;
    __syncthreads();

    for (int i = t; i < LL; i += 256) {
        unsigned k = __float_as_uint(mrow[i]);
        k ^= (k & 0x80000000u) ? 0xFFFFFFFFu : 0x80000000u;  // order-preserving
        keys[i] = k;
        atomicAdd(&hist[k >> 20], 1);
    }
    __syncthreads();

    {
        int s = 0;
        #pragma unroll
        for (int j = 0; j < 16; ++j) s += hist[t * 16 + j];
        csum_s[t] = s;
    }
    __syncthreads();
    for (int off = 1; off < 256; off <<= 1) {
        int v = csum_s[t] + ((t + off < 256) ? csum_s[t + off] : 0);
        __syncthreads();
        csum_s[t] = v;
        __syncthreads();
    }
    if (csum_s[t] >= u && (t == 255 || csum_s[t + 1] < u)) {
        int acc = (t < 255) ? csum_s[t + 1] : 0;
        int B = t * 16;
        for (int b2 = t * 16 + 15; b2 >= t * 16; --b2) {
            int nb = acc + hist[b2];
            if (nb >= u) { B = b2; break; }
            acc = nb;
        }
        ctl[0] = B; ctl[1] = acc;
    }
    __syncthreads();
    int B = ctl[0], c_hi = ctl[1];
    int* ckey = hist;
    __syncthreads();

    for (int i = t; i < LL; i += 256) {
        unsigned k = keys[i];
        int bk = k >> 20;
        if (bk > B) {
            int slot = atomicAdd(&ctl[2], 1);
            Mtop[bh * u + slot] = i;
        } else if (bk == B) {
            int c = atomicAdd(&ctl[3], 1);
            cidx[c] = i; ckey[c] = (int)k;
        }
    }
    __syncthreads();

    if (t < 64) {
        int need = u - c_hi;
        int nc = ctl[3];
        for (int it = 0; it < need; ++it) {
            unsigned bk = 0; int bi = 0x7fffffff;
            for (int j = t; j < nc; j += 64) {
                unsigned k = (unsigned)ckey[j];
                if (k > bk || (k == bk && cidx[j] < bi)) { bk = k; bi = cidx[j]; }
            }
            #pragma unroll
            for (int off = 1; off < 64; off <<= 1) {
                unsigned ok = (unsigned)__shfl_xor((int)bk, off, 64);
                int oi = __shfl_xor(bi, off, 64);
                if (ok > bk || (ok == bk && oi < bi)) { bk = ok; bi = oi; }
            }
            if (t == 0) Mtop[bh * u + c_hi + it] = bi;
            for (int j = t; j < nc; j += 64)
                if (cidx[j] == bi) ckey[j] = 0;
        }
    }
}

// ---------------------------------------------------------------------------
// D3: tiled flash partial attention, templated on segment length SL.
// SL=128 -> LDS 73.4KB -> 2 blocks/CU. XCD-swizzled grid.
// ---------------------------------------------------------------------------
template<int SL>
__global__ __launch_bounds__(256) void kernelAttnSegT(
        const float* __restrict__ Q, const float* __restrict__ K,
        const float* __restrict__ V, const int* __restrict__ Mtop,
        float* __restrict__ accs, float* __restrict__ ms, int u) {
    constexpr int NSEG = LL / SL;
    constexpr int JN = SL / 16;
    __shared__ float Qs[QP][KP];
    __shared__ float KVs[SL * KP];
    __shared__ float Ps[QP][SL + 4];
    __shared__ int qpos_s[QP];

    int w = blockIdx.x;
    int bh  = ((w & 7) << 1) | ((w >> 3) & 1);
    int seg = w >> 4;
    int h = bh & (HH - 1), b = bh >> 3;
    int k0 = seg * SL;
    int t = threadIdx.x;

    if (t < QP) qpos_s[t] = (t < u) ? Mtop[bh * u + t] : -1;
    __syncthreads();

    for (int i = t; i < QP * 16; i += 256) {
        int q = i >> 4, f4 = i & 15;
        float4 val = make_float4(0.f, 0.f, 0.f, 0.f);
        if (q < u) {
            int qpos = qpos_s[q];
            val = *(const float4*)(Q + (((size_t)b * LL + qpos) * HH + h) * DD + f4 * 4);
        }
        *(float4*)&Qs[q][f4 * 4] = val;
    }
    for (int i = t; i < SL * 16; i += 256) {
        int k = i >> 4, f4 = i & 15;
        *(float4*)&KVs[k * KP + f4 * 4] =
            *(const float4*)(K + (((size_t)b * LL + k0 + k) * HH + h) * DD + f4 * 4);
    }
    __syncthreads();

    int tq = t & 15, tk = t >> 4;
    float acc[3][JN];
    #pragma unroll
    for (int i = 0; i < 3; ++i)
        #pragma unroll
        for (int j = 0; j < JN; ++j) acc[i][j] = 0.f;
    for (int d4 = 0; d4 < 16; ++d4) {
        float4 qa = *(const float4*)&Qs[tq][d4 * 4];
        float4 qb = *(const float4*)&Qs[tq + 16][d4 * 4];
        float4 qc = *(const float4*)&Qs[tq + 32][d4 * 4];
        #pragma unroll
        for (int j = 0; j < JN; ++j) {
            float4 kv = *(const float4*)&KVs[(tk + 16 * j) * KP + d4 * 4];
            acc[0][j] += dot4(qa, kv);
            acc[1][j] += dot4(qb, kv);
            acc[2][j] += dot4(qc, kv);
        }
    }
    #pragma unroll
    for (int i = 0; i < 3; ++i) {
        int q = tq + 16 * i;
        int qp = qpos_s[q];
        #pragma unroll
        for (int j = 0; j < JN; ++j) {
            int kg = k0 + tk + 16 * j;
            Ps[q][tk + 16 * j] = (kg <= qp) ? acc[i][j] * 0.125f : -INFINITY;
        }
    }
    __syncthreads();

    for (int i = t; i < SL * 16; i += 256) {
        int k = i >> 4, f4 = i & 15;
        *(float4*)&KVs[k * 64 + f4 * 4] =
            *(const float4*)(V + (((size_t)b * LL + k0 + k) * HH + h) * DD + f4 * 4);
    }

    {
        int r = t >> 2, part = t & 3;
        if (r < QP) {
            float m = -INFINITY;
            int c0 = part * JN;
            #pragma unroll
            for (int c4 = 0; c4 < JN; ++c4) {
                float4 p = *(const float4*)&Ps[r][(c0 + c4) * 4];
                m = fmaxf(m, fmaxf(fmaxf(p.x, p.y), fmaxf(p.z, p.w)));
            }
            m = fmaxf(m, __shfl_xor(m, 1, 64));
            m = fmaxf(m, __shfl_xor(m, 2, 64));
            float sum = 0.f;
            #pragma unroll
            for (int c4 = 0; c4 < JN; ++c4) {
                float4 p = *(const float4*)&Ps[r][(c0 + c4) * 4];
                p.x = __expf(p.x - m); p.y = __expf(p.y - m);
                p.z = __expf(p.z - m); p.w = __expf(p.w - m);
                *(float4*)&Ps[r][(c0 + c4) * 4] = p;
                sum += p.x + p.y + p.z + p.w;
            }
            sum += __shfl_xor(sum, 1, 64);
            sum += __shfl_xor(sum, 2, 64);
            if (part == 0 && r < u) {
                ms[((size_t)(bh * u + r) * NSEG + seg) * 2 + 0] = m;
                ms[((size_t)(bh * u + r) * NSEG + seg) * 2 + 1] = sum;
            }
        }
    }
    __syncthreads();

    {
        int tq2 = t & 15, td = t >> 4;
        float4 o0 = make_float4(0,0,0,0), o1 = o0, o2 = o0;
        for (int k4 = 0; k4 < SL / 4; ++k4) {
            float4 p0 = *(const float4*)&Ps[tq2][k4 * 4];
            float4 p1 = *(const float4*)&Ps[tq2 + 16][k4 * 4];
            float4 p2 = *(const float4*)&Ps[tq2 + 32][k4 * 4];
            float4 v0 = *(const float4*)&KVs[(k4 * 4 + 0) * 64 + td * 4];
            float4 v1 = *(const float4*)&KVs[(k4 * 4 + 1) * 64 + td * 4];
            float4 v2 = *(const float4*)&KVs[(k4 * 4 + 2) * 64 + td * 4];
            float4 v3 = *(const float4*)&KVs[(k4 * 4 + 3) * 64 + td * 4];
            o0.x += p0.x*v0.x + p0.y*v1.x + p0.z*v2.x + p0.w*v3.x;
            o0.y += p0.x*v0.y + p0.y*v1.y + p0.z*v2.y + p0.w*v3.y;
            o0.z += p0.x*v0.z + p0.y*v1.z + p0.z*v2.z + p0.w*v3.z;
            o0.w += p0.x*v0.w + p0.y*v1.w + p0.z*v2.w + p0.w*v3.w;
            o1.x += p1.x*v0.x + p1.y*v1.x + p1.z*v2.x + p1.w*v3.x;
            o1.y += p1.x*v0.y + p1.y*v1.y + p1.z*v2.y + p1.w*v3.y;
            o1.z += p1.x*v0.z + p1.y*v1.z + p1.z*v2.z + p1.w*v3.z;
            o1.w += p1.x*v0.w + p1.y*v1.w + p1.z*v2.w + p1.w*v3.w;
            o2.x += p2.x*v0.x + p2.y*v1.x + p2.z*v2.x + p2.w*v3.x;
            o2.y += p2.x*v0.y + p2.y*v1.y + p2.z*v2.y + p2.w*v3.y;
            o2.z += p2.x*v0.z + p2.y*v1.z + p2.z*v2.z + p2.w*v3.z;
            o2.w += p2.x*v0.w + p2.y*v1.w + p2.z*v2.w + p2.w*v3.w;
        }
        if (tq2 < u)
            *(float4*)&accs[((size_t)(bh * u + tq2) * NSEG + seg) * DD + td * 4] = o0;
        if (tq2 + 16 < u)
            *(float4*)&accs[((size_t)(bh * u + tq2 + 16) * NSEG + seg) * DD + td * 4] = o1;
        if (tq2 + 32 < u)
            *(float4*)&accs[((size_t)(bh * u + tq2 + 32) * NSEG + seg) * DD + td * 4] = o2;
    }
}

// ---------------------------------------------------------------------------
// D4: merge segment partials, overwrite the selected rows in out.
// ---------------------------------------------------------------------------
template<int SL>
__global__ __launch_bounds__(64) void kernelAttnCombineT(const int* __restrict__ Mtop,
                                  const float* __restrict__ accs,
                                  const float* __restrict__ ms,
                                  float* __restrict__ out, int u) {
    constexpr int NSEG = LL / SL;
    int qid = blockIdx.x;
    int lane = threadIdx.x;
    int bh = qid / u;
    int qpos = Mtop[qid];
    int nseg = qpos / SL + 1;
    float gmax = -INFINITY;
    for (int s = 0; s < nseg; ++s)
        gmax = fmaxf(gmax, ms[((size_t)qid * NSEG + s) * 2 + 0]);
    float denom = 0.f, acc = 0.f;
    for (int s = 0; s < nseg; ++s) {
        float m_ = ms[((size_t)qid * NSEG + s) * 2 + 0];
        float e_ = ms[((size_t)qid * NSEG + s) * 2 + 1];
        float f = __expf(m_ - gmax);
        denom += e_ * f;
        acc += accs[((size_t)qid * NSEG + s) * DD + lane] * f;
    }
    out[((size_t)bh * LL + qpos) * DD + lane] = acc / denom;
}

// ---------------------------------------------------------------------------
extern "C" void kernel_launch(void* const* d_in, const int* in_sizes, int n_in,
                              void* d_out, int out_size, void* d_ws, size_t ws_size,
                              hipStream_t stream) {
    const float* Q  = (const float*)d_in[0];
    const float* K  = (const float*)d_in[1];
    const float* V  = (const float*)d_in[2];
    const int* idx  = (const int*)d_in[3];
    float* out = (float*)d_out;

    int u = in_sizes[3] / LL;                 // u == 45 here
    int nq = BH * u;

    char* ws = (char*)d_ws;
    size_t base = (size_t)BH * LL * 4 + 65536 + (size_t)BH * NCHUNK * DD * 4;
    float* M    = (float*)ws;
    int*   Mtop = (int*)(ws + (size_t)BH * LL * 4);
    float* csum = (float*)(ws + (size_t)BH * LL * 4 + 65536);
    float* accs = (float*)(ws + base);

    size_t need128 = base + (size_t)nq * 32 * DD * 4 + (size_t)nq * 32 * 2 * 4;
    bool sl128 = (ws_size >= need128);
    int nsegs = sl128 ? 32 : 16;
    float* msp = (float*)(ws + base + (size_t)nq * nsegs * DD * 4);

    int nit = (u + 15) / 16;
    int g1 = NCB + MTBLOCKS;                  // 512 chunksum (front) + 16384 MT

    if      (nit == 3) fusedChunkMT<3><<<g1, 256, 0, stream>>>(Q, K, idx, M, V, csum, u);
    else if (nit == 1) fusedChunkMT<1><<<g1, 256, 0, stream>>>(Q, K, idx, M, V, csum, u);
    else if (nit == 2) fusedChunkMT<2><<<g1, 256, 0, stream>>>(Q, K, idx, M, V, csum, u);
    else if (nit == 4) fusedChunkMT<4><<<g1, 256, 0, stream>>>(Q, K, idx, M, V, csum, u);
    else {
        kernelMGen<<<MTBLOCKS, 256, 0, stream>>>(Q, K, idx, M, u);
        kernelChunkOnly<<<NCB, 256, 0, stream>>>(V, csum);
    }

    fusedTopKCumsum<<<16 + NCB, 256, 0, stream>>>(M, Mtop, V, csum, out, u);

    if (sl128) {
        kernelAttnSegT<128><<<BH * 32, 256, 0, stream>>>(Q, K, V, Mtop, accs, msp, u);
        kernelAttnCombineT<128><<<nq, 64, 0, stream>>>(Mtop, accs, msp, out, u);
    } else {
        kernelAttnSegT<256><<<BH * 16, 256, 0, stream>>>(Q, K, V, Mtop, accs, msp, u);
        kernelAttnCombineT<256><<<nq, 64, 0, stream>>>(Mtop, accs, msp, out, u);
    }
}

// Round 18
// 107.086 us; speedup vs baseline: 1.0517x; 1.0517x over previous
//
#include <hip/hip_runtime.h>
#include <math.h>

#define BB 2
#define LL 4096
#define HH 8
#define DD 64
#define BH (BB*HH)
#define NCHUNK 64
#define CLEN (LL/NCHUNK)
#define QP 48          // u=45 padded to 48
#define KP 68          // padded row length (floats) for Q/K tiles
#define MTBLOCKS (BH*LL/4)   // 16384

__device__ __forceinline__ float dot4(float4 a, float4 b) {
    return a.x*b.x + a.y*b.y + a.z*b.z + a.w*b.w;
}

// ---------------------------------------------------------------------------
// D1: blocks 0..255 = V chunk sums FRONT-placed (fills CUs during MT ramp;
// r14/15 lesson: trailing fused blocks serialize, leading ones hide).
// Blocks 256..16639 = MT (one wave per query, XCD-local bh pairing, NIT
// unroll, coalesced fragments; ~53us = random-L2-line-rate floor, r7-12).
// ---------------------------------------------------------------------------
template<int NIT>
__global__ __launch_bounds__(256) void fusedChunkMT(const float* __restrict__ Q,
        const float* __restrict__ K, const int* __restrict__ idx,
        float* __restrict__ M, const float* __restrict__ V,
        float* __restrict__ csum, int u) {
    int t = threadIdx.x;
    if (blockIdx.x < 256) {
        int id = blockIdx.x * 4 + (t >> 6);               // bh*NCHUNK + c
        int lane = t & 63;
        int c = id & (NCHUNK - 1);
        int bh = id >> 6;
        int h = bh & (HH - 1), b = bh >> 3;
        int l0 = c * CLEN;
        float acc = 0.f;
        for (int i = 0; i < CLEN; ++i)
            acc += V[(((size_t)b * LL + l0 + i) * HH + h) * DD + lane];
        csum[(size_t)id * DD + lane] = acc;
        return;
    }
    int wave = t >> 6;
    int lane = t & 63;
    int w = blockIdx.x - 256;
    int bh = ((w & 7) << 1) | ((w >> 3) & 1);   // XCD-local bh pair
    int qb = w >> 4;                            // 0..1023
    int g  = (bh << 12) + qb * 4 + wave;        // (b*H+h)*L + l
    int l  = g & (LL - 1);
    int h  = bh & (HH - 1);
    int b  = bh >> 3;
    int grp = lane >> 2, sub = lane & 3;
    const float4* qrow = (const float4*)(Q + (((size_t)b * LL + l) * HH + h) * DD);
    float4 q0 = qrow[0 * 4 + sub];
    float4 q1 = qrow[1 * 4 + sub];
    float4 q2 = qrow[2 * 4 + sub];
    float4 q3 = qrow[3 * 4 + sub];
    const int* ip = idx + (size_t)l * u;

    int  ks[NIT];
    bool act[NIT];
    #pragma unroll
    for (int i = 0; i < NIT; ++i) {
        int s = i * 16 + grp;
        act[i] = (s < u);
        ks[i] = act[i] ? ip[s] : 0;
    }
    const float* kbase = K + ((size_t)b * LL * HH + h) * DD;
    float4 kv[NIT][4];
    #pragma unroll
    for (int i = 0; i < NIT; ++i) {
        const float4* kr = (const float4*)(kbase + (size_t)ks[i] * (HH * DD));
        kv[i][0] = kr[0 * 4 + sub];
        kv[i][1] = kr[1 * 4 + sub];
        kv[i][2] = kr[2 * 4 + sub];
        kv[i][3] = kr[3 * 4 + sub];
    }
    float mx = -INFINITY, sm = 0.f;
    #pragma unroll
    for (int i = 0; i < NIT; ++i) {
        float p = dot4(q0, kv[i][0]) + dot4(q1, kv[i][1])
                + dot4(q2, kv[i][2]) + dot4(q3, kv[i][3]);
        p += __shfl_xor(p, 1, 64);
        p += __shfl_xor(p, 2, 64);
        if (act[i]) { mx = fmaxf(mx, p); sm += p; }
    }
    #pragma unroll
    for (int off = 4; off <= 32; off <<= 1) {
        mx = fmaxf(mx, __shfl_xor(mx, off, 64));
        sm += __shfl_xor(sm, off, 64);
    }
    if (lane == 0) M[g] = mx - sm * (1.0f / LL);
}

// fallbacks for u > 64
__global__ void kernelMGen(const float* __restrict__ Q, const float* __restrict__ K,
                        const int* __restrict__ idx, float* __restrict__ M, int u) {
    int wave = threadIdx.x >> 6;
    int lane = threadIdx.x & 63;
    int g = blockIdx.x * 4 + wave;
    int l  = g & (LL - 1);
    int bh = g >> 12;
    int h  = bh & (HH - 1);
    int b  = bh >> 3;
    int grp = lane >> 2, sub = lane & 3;
    const float4* qrow = (const float4*)(Q + (((size_t)b * LL + l) * HH + h) * DD);
    float4 q0 = qrow[0*4+sub], q1 = qrow[1*4+sub];
    float4 q2 = qrow[2*4+sub], q3 = qrow[3*4+sub];
    const int* ip = idx + (size_t)l * u;
    float mx = -INFINITY, sm = 0.f;
    for (int s0 = 0; s0 < u; s0 += 16) {
        int s = s0 + grp;
        bool act = (s < u);
        int ks = act ? ip[s] : 0;
        const float4* krow = (const float4*)(K + (((size_t)b * LL + ks) * HH + h) * DD);
        float4 k0 = krow[0*4+sub], k1 = krow[1*4+sub];
        float4 k2 = krow[2*4+sub], k3 = krow[3*4+sub];
        float p = dot4(q0, k0) + dot4(q1, k1) + dot4(q2, k2) + dot4(q3, k3);
        p += __shfl_xor(p, 1, 64);
        p += __shfl_xor(p, 2, 64);
        if (act) { mx = fmaxf(mx, p); sm += p; }
    }
    #pragma unroll
    for (int off = 4; off <= 32; off <<= 1) {
        mx = fmaxf(mx, __shfl_xor(mx, off, 64));
        sm += __shfl_xor(sm, off, 64);
    }
    if (lane == 0) M[g] = mx - sm * (1.0f / LL);
}

__global__ void kernelChunkOnly(const float* __restrict__ V, float* __restrict__ csum) {
    int id = blockIdx.x * 4 + (threadIdx.x >> 6);
    int lane = threadIdx.x & 63;
    int c = id & (NCHUNK - 1);
    int bh = id >> 6;
    int h = bh & (HH - 1), b = bh >> 3;
    int l0 = c * CLEN;
    float acc = 0.f;
    for (int i = 0; i < CLEN; ++i)
        acc += V[(((size_t)b * LL + l0 + i) * HH + h) * DD + lane];
    csum[(size_t)id * DD + lane] = acc;
}

// ---------------------------------------------------------------------------
// D2: blocks 0-15 = radix-select top-u per (b,h); blocks 16+ = cumsum emit
// for ALL rows (self-computed prefix; selected rows overwritten by D4).
// ---------------------------------------------------------------------------
__global__ __launch_bounds__(256) void fusedTopKCumsum(const float* __restrict__ M,
        int* __restrict__ Mtop, const float* __restrict__ V,
        const float* __restrict__ csum, float* __restrict__ out, int u) {
    __shared__ unsigned keys[LL];
    __shared__ int hist[4096];
    __shared__ int cidx[LL];
    __shared__ int csum_s[256];
    __shared__ int ctl[4];
    int t = threadIdx.x;

    if (blockIdx.x >= 16) {
        int id = (blockIdx.x - 16) * 4 + (t >> 6);
        int lane = t & 63;
        int c = id & (NCHUNK - 1);
        int bh = id >> 6;
        int h = bh & (HH - 1), b = bh >> 3;
        float acc = 0.f;
        for (int cc = 0; cc < c; ++cc)
            acc += csum[((size_t)(bh * NCHUNK + cc)) * DD + lane];
        int l0 = c * CLEN;
        for (int i = 0; i < CLEN; ++i) {
            int l = l0 + i;
            acc += V[(((size_t)b * LL + l) * HH + h) * DD + lane];
            out[((size_t)bh * LL + l) * DD + lane] = acc;
        }
        return;
    }

    int bh = blockIdx.x;
    const float* mrow = M + (size_t)bh * LL;
    for (int i = t; i < 4096; i += 256) hist[i] = 0;
    if (t < 4) ctl[t] = 0;
    __syncthreads();

    for (int i = t; i < LL; i += 256) {
        unsigned k = __float_as_uint(mrow[i]);
        k ^= (k & 0x80000000u) ? 0xFFFFFFFFu : 0x80000000u;  // order-preserving
        keys[i] = k;
        atomicAdd(&hist[k >> 20], 1);
    }
    __syncthreads();

    {
        int s = 0;
        #pragma unroll
        for (int j = 0; j < 16; ++j) s += hist[t * 16 + j];
        csum_s[t] = s;
    }
    __syncthreads();
    for (int off = 1; off < 256; off <<= 1) {
        int v = csum_s[t] + ((t + off < 256) ? csum_s[t + off] : 0);
        __syncthreads();
        csum_s[t] = v;
        __syncthreads();
    }
    if (csum_s[t] >= u && (t == 255 || csum_s[t + 1] < u)) {
        int acc = (t < 255) ? csum_s[t + 1] : 0;
        int B = t * 16;
        for (int b2 = t * 16 + 15; b2 >= t * 16; --b2) {
            int nb = acc + hist[b2];
            if (nb >= u) { B = b2; break; }
            acc = nb;
        }
        ctl[0] = B; ctl[1] = acc;
    }
    __syncthreads();
    int B = ctl[0], c_hi = ctl[1];
    int* ckey = hist;
    __syncthreads();

    for (int i = t; i < LL; i += 256) {
        unsigned k = keys[i];
        int bk = k >> 20;
        if (bk > B) {
            int slot = atomicAdd(&ctl[2], 1);
            Mtop[bh * u + slot] = i;
        } else if (bk == B) {
            int c = atomicAdd(&ctl[3], 1);
            cidx[c] = i; ckey[c] = (int)k;
        }
    }
    __syncthreads();

    if (t < 64) {
        int need = u - c_hi;
        int nc = ctl[3];
        for (int it = 0; it < need; ++it) {
            unsigned bk = 0; int bi = 0x7fffffff;
            for (int j = t; j < nc; j += 64) {
                unsigned k = (unsigned)ckey[j];
                if (k > bk || (k == bk && cidx[j] < bi)) { bk = k; bi = cidx[j]; }
            }
            #pragma unroll
            for (int off = 1; off < 64; off <<= 1) {
                unsigned ok = (unsigned)__shfl_xor((int)bk, off, 64);
                int oi = __shfl_xor(bi, off, 64);
                if (ok > bk || (ok == bk && oi < bi)) { bk = ok; bi = oi; }
            }
            if (t == 0) Mtop[bh * u + c_hi + it] = bi;
            for (int j = t; j < nc; j += 64)
                if (cidx[j] == bi) ckey[j] = 0;
        }
    }
}

// ---------------------------------------------------------------------------
// D3: tiled flash partial attention, templated on segment length SL.
// SL=128 -> LDS 73.4KB -> 2 blocks/CU. XCD-swizzled grid.
// ---------------------------------------------------------------------------
template<int SL>
__global__ __launch_bounds__(256) void kernelAttnSegT(
        const float* __restrict__ Q, const float* __restrict__ K,
        const float* __restrict__ V, const int* __restrict__ Mtop,
        float* __restrict__ accs, float* __restrict__ ms, int u) {
    constexpr int NSEG = LL / SL;
    constexpr int JN = SL / 16;
    __shared__ float Qs[QP][KP];
    __shared__ float KVs[SL * KP];
    __shared__ float Ps[QP][SL + 4];
    __shared__ int qpos_s[QP];

    int w = blockIdx.x;
    int bh  = ((w & 7) << 1) | ((w >> 3) & 1);
    int seg = w >> 4;
    int h = bh & (HH - 1), b = bh >> 3;
    int k0 = seg * SL;
    int t = threadIdx.x;

    if (t < QP) qpos_s[t] = (t < u) ? Mtop[bh * u + t] : -1;
    __syncthreads();

    for (int i = t; i < QP * 16; i += 256) {
        int q = i >> 4, f4 = i & 15;
        float4 val = make_float4(0.f, 0.f, 0.f, 0.f);
        if (q < u) {
            int qpos = qpos_s[q];
            val = *(const float4*)(Q + (((size_t)b * LL + qpos) * HH + h) * DD + f4 * 4);
        }
        *(float4*)&Qs[q][f4 * 4] = val;
    }
    for (int i = t; i < SL * 16; i += 256) {
        int k = i >> 4, f4 = i & 15;
        *(float4*)&KVs[k * KP + f4 * 4] =
            *(const float4*)(K + (((size_t)b * LL + k0 + k) * HH + h) * DD + f4 * 4);
    }
    __syncthreads();

    int tq = t & 15, tk = t >> 4;
    float acc[3][JN];
    #pragma unroll
    for (int i = 0; i < 3; ++i)
        #pragma unroll
        for (int j = 0; j < JN; ++j) acc[i][j] = 0.f;
    for (int d4 = 0; d4 < 16; ++d4) {
        float4 qa = *(const float4*)&Qs[tq][d4 * 4];
        float4 qb = *(const float4*)&Qs[tq + 16][d4 * 4];
        float4 qc = *(const float4*)&Qs[tq + 32][d4 * 4];
        #pragma unroll
        for (int j = 0; j < JN; ++j) {
            float4 kv = *(const float4*)&KVs[(tk + 16 * j) * KP + d4 * 4];
            acc[0][j] += dot4(qa, kv);
            acc[1][j] += dot4(qb, kv);
            acc[2][j] += dot4(qc, kv);
        }
    }
    #pragma unroll
    for (int i = 0; i < 3; ++i) {
        int q = tq + 16 * i;
        int qp = qpos_s[q];
        #pragma unroll
        for (int j = 0; j < JN; ++j) {
            int kg = k0 + tk + 16 * j;
            Ps[q][tk + 16 * j] = (kg <= qp) ? acc[i][j] * 0.125f : -INFINITY;
        }
    }
    __syncthreads();

    for (int i = t; i < SL * 16; i += 256) {
        int k = i >> 4, f4 = i & 15;
        *(float4*)&KVs[k * 64 + f4 * 4] =
            *(const float4*)(V + (((size_t)b * LL + k0 + k) * HH + h) * DD + f4 * 4);
    }

    {
        int r = t >> 2, part = t & 3;
        if (r < QP) {
            float m = -INFINITY;
            int c0 = part * JN;
            #pragma unroll
            for (int c4 = 0; c4 < JN; ++c4) {
                float4 p = *(const float4*)&Ps[r][(c0 + c4) * 4];
                m = fmaxf(m, fmaxf(fmaxf(p.x, p.y), fmaxf(p.z, p.w)));
            }
            m = fmaxf(m, __shfl_xor(m, 1, 64));
            m = fmaxf(m, __shfl_xor(m, 2, 64));
            float sum = 0.f;
            #pragma unroll
            for (int c4 = 0; c4 < JN; ++c4) {
                float4 p = *(const float4*)&Ps[r][(c0 + c4) * 4];
                p.x = __expf(p.x - m); p.y = __expf(p.y - m);
                p.z = __expf(p.z - m); p.w = __expf(p.w - m);
                *(float4*)&Ps[r][(c0 + c4) * 4] = p;
                sum += p.x + p.y + p.z + p.w;
            }
            sum += __shfl_xor(sum, 1, 64);
            sum += __shfl_xor(sum, 2, 64);
            if (part == 0 && r < u) {
                ms[((size_t)(bh * u + r) * NSEG + seg) * 2 + 0] = m;
                ms[((size_t)(bh * u + r) * NSEG + seg) * 2 + 1] = sum;
            }
        }
    }
    __syncthreads();

    {
        int tq2 = t & 15, td = t >> 4;
        float4 o0 = make_float4(0,0,0,0), o1 = o0, o2 = o0;
        for (int k4 = 0; k4 < SL / 4; ++k4) {
            float4 p0 = *(const float4*)&Ps[tq2][k4 * 4];
            float4 p1 = *(const float4*)&Ps[tq2 + 16][k4 * 4];
            float4 p2 = *(const float4*)&Ps[tq2 + 32][k4 * 4];
            float4 v0 = *(const float4*)&KVs[(k4 * 4 + 0) * 64 + td * 4];
            float4 v1 = *(const float4*)&KVs[(k4 * 4 + 1) * 64 + td * 4];
            float4 v2 = *(const float4*)&KVs[(k4 * 4 + 2) * 64 + td * 4];
            float4 v3 = *(const float4*)&KVs[(k4 * 4 + 3) * 64 + td * 4];
            o0.x += p0.x*v0.x + p0.y*v1.x + p0.z*v2.x + p0.w*v3.x;
            o0.y += p0.x*v0.y + p0.y*v1.y + p0.z*v2.y + p0.w*v3.y;
            o0.z += p0.x*v0.z + p0.y*v1.z + p0.z*v2.z + p0.w*v3.z;
            o0.w += p0.x*v0.w + p0.y*v1.w + p0.z*v2.w + p0.w*v3.w;
            o1.x += p1.x*v0.x + p1.y*v1.x + p1.z*v2.x + p1.w*v3.x;
            o1.y += p1.x*v0.y + p1.y*v1.y + p1.z*v2.y + p1.w*v3.y;
            o1.z += p1.x*v0.z + p1.y*v1.z + p1.z*v2.z + p1.w*v3.z;
            o1.w += p1.x*v0.w + p1.y*v1.w + p1.z*v2.w + p1.w*v3.w;
            o2.x += p2.x*v0.x + p2.y*v1.x + p2.z*v2.x + p2.w*v3.x;
            o2.y += p2.x*v0.y + p2.y*v1.y + p2.z*v2.y + p2.w*v3.y;
            o2.z += p2.x*v0.z + p2.y*v1.z + p2.z*v2.z + p2.w*v3.z;
            o2.w += p2.x*v0.w + p2.y*v1.w + p2.z*v2.w + p2.w*v3.w;
        }
        if (tq2 < u)
            *(float4*)&accs[((size_t)(bh * u + tq2) * NSEG + seg) * DD + td * 4] = o0;
        if (tq2 + 16 < u)
            *(float4*)&accs[((size_t)(bh * u + tq2 + 16) * NSEG + seg) * DD + td * 4] = o1;
        if (tq2 + 32 < u)
            *(float4*)&accs[((size_t)(bh * u + tq2 + 32) * NSEG + seg) * DD + td * 4] = o2;
    }
}

// ---------------------------------------------------------------------------
// D4: merge segment partials, overwrite the selected rows in out.
// ---------------------------------------------------------------------------
template<int SL>
__global__ __launch_bounds__(64) void kernelAttnCombineT(const int* __restrict__ Mtop,
                                  const float* __restrict__ accs,
                                  const float* __restrict__ ms,
                                  float* __restrict__ out, int u) {
    constexpr int NSEG = LL / SL;
    int qid = blockIdx.x;
    int lane = threadIdx.x;
    int bh = qid / u;
    int qpos = Mtop[qid];
    int nseg = qpos / SL + 1;
    float gmax = -INFINITY;
    for (int s = 0; s < nseg; ++s)
        gmax = fmaxf(gmax, ms[((size_t)qid * NSEG + s) * 2 + 0]);
    float denom = 0.f, acc = 0.f;
    for (int s = 0; s < nseg; ++s) {
        float m_ = ms[((size_t)qid * NSEG + s) * 2 + 0];
        float e_ = ms[((size_t)qid * NSEG + s) * 2 + 1];
        float f = __expf(m_ - gmax);
        denom += e_ * f;
        acc += accs[((size_t)qid * NSEG + s) * DD + lane] * f;
    }
    out[((size_t)bh * LL + qpos) * DD + lane] = acc / denom;
}

// ---------------------------------------------------------------------------
extern "C" void kernel_launch(void* const* d_in, const int* in_sizes, int n_in,
                              void* d_out, int out_size, void* d_ws, size_t ws_size,
                              hipStream_t stream) {
    const float* Q  = (const float*)d_in[0];
    const float* K  = (const float*)d_in[1];
    const float* V  = (const float*)d_in[2];
    const int* idx  = (const int*)d_in[3];
    float* out = (float*)d_out;

    int u = in_sizes[3] / LL;                 // u == 45 here
    int nq = BH * u;

    char* ws = (char*)d_ws;
    size_t base = (size_t)BH * LL * 4 + 65536 + (size_t)BH * NCHUNK * DD * 4;
    float* M    = (float*)ws;
    int*   Mtop = (int*)(ws + (size_t)BH * LL * 4);
    float* csum = (float*)(ws + (size_t)BH * LL * 4 + 65536);
    float* accs = (float*)(ws + base);

    size_t need128 = base + (size_t)nq * 32 * DD * 4 + (size_t)nq * 32 * 2 * 4;
    bool sl128 = (ws_size >= need128);
    int nsegs = sl128 ? 32 : 16;
    float* msp = (float*)(ws + base + (size_t)nq * nsegs * DD * 4);

    int nit = (u + 15) / 16;
    int g1 = 256 + MTBLOCKS;                  // 256 chunksum (front) + 16384 MT

    if      (nit == 3) fusedChunkMT<3><<<g1, 256, 0, stream>>>(Q, K, idx, M, V, csum, u);
    else if (nit == 1) fusedChunkMT<1><<<g1, 256, 0, stream>>>(Q, K, idx, M, V, csum, u);
    else if (nit == 2) fusedChunkMT<2><<<g1, 256, 0, stream>>>(Q, K, idx, M, V, csum, u);
    else if (nit == 4) fusedChunkMT<4><<<g1, 256, 0, stream>>>(Q, K, idx, M, V, csum, u);
    else {
        kernelMGen<<<MTBLOCKS, 256, 0, stream>>>(Q, K, idx, M, u);
        kernelChunkOnly<<<BH * NCHUNK / 4, 256, 0, stream>>>(V, csum);
    }

    fusedTopKCumsum<<<16 + BH * NCHUNK / 4, 256, 0, stream>>>(M, Mtop, V, csum, out, u);

    if (sl128) {
        kernelAttnSegT<128><<<BH * 32, 256, 0, stream>>>(Q, K, V, Mtop, accs, msp, u);
        kernelAttnCombineT<128><<<nq, 64, 0, stream>>>(Mtop, accs, msp, out, u);
    } else {
        kernelAttnSegT<256><<<BH * 16, 256, 0, stream>>>(Q, K, V, Mtop, accs, msp, u);
        kernelAttnCombineT<256><<<nq, 64, 0, stream>>>(Mtop, accs, msp, out, u);
    }
}